// Round 2
// baseline (4039.309 us; speedup 1.0000x reference)
//
#include <hip/hip_runtime.h>
#include <hip/hip_bf16.h>

#define B_ 4
#define S_ 512
#define D_ 512
#define I_ 1024
#define C_ 32
#define NC_ 16

// ---- ws layout (float offsets) ----
#define KBUF (B_*S_*D_)              // 1048576
#define STSZ (B_*I_*D_)              // 2097152
#define HSZ  (B_*I_*C_)              // 131072
#define DOSZ (B_*C_*D_)              // 65536
#define OFF_K    0
#define OFF_V    (OFF_K + KBUF)
#define OFF_Q    (OFF_V + KBUF)
#define OFF_TH   (OFF_Q + KBUF)
#define OFF_AL   (OFF_TH + B_*S_)
#define OFF_ET   (OFF_AL + B_*S_)
#define OFF_KN2  (OFF_ET + B_*S_)
#define OFF_SW1  (OFF_KN2 + B_*S_)
#define OFF_MW1  (OFF_SW1 + STSZ)
#define OFF_SW2  (OFF_MW1 + STSZ)
#define OFF_MW2  (OFF_SW2 + STSZ)
#define OFF_SLN  (OFF_MW2 + STSZ)
#define OFF_MLN  (OFF_SLN + B_*D_)
#define OFF_H2   (OFF_MLN + B_*D_)
#define OFF_Z1   (OFF_H2 + 2*HSZ)
#define OFF_DHP  (OFF_Z1 + HSZ)
#define OFF_DO   (OFF_DHP + HSZ)
#define OFF_DLN  (OFF_DO + DOSZ)
#define OFF_OB   (OFF_DLN + DOSZ)
#define OFF_SLAB (OFF_OB + DOSZ)
#define SLABSTR  256
// per (c,b) slab: +0 hn[32] +32 sqd[32] +64 don2[32] +96 dln2[32] +128 sE[32] +160 sC[32] +192 PE +193 PB +194 Q
#define OFF_TICK (OFF_SLAB + NC_*B_*SLABSTR)
#define OFF_FLAG (OFF_TICK + 64)
// aliases (regions dead after the chunk loop)
#define OFF_HQ   OFF_K      // 2,097,152 floats = K+V exactly; Q untouched
#define OFF_ORET OFF_SW1    // 1,048,576 < STSZ; MW1 untouched

__device__ __forceinline__ float bf2f(__hip_bfloat16 v){ return __bfloat162float(v); }
__device__ __forceinline__ float ldin(const void* p, size_t i, int f){
  return f ? ((const float*)p)[i] : bf2f(((const __hip_bfloat16*)p)[i]);
}

__device__ __forceinline__ float blockReduceSum(float v, float* sm){
  #pragma unroll
  for(int o=32;o>0;o>>=1) v += __shfl_down(v,o,64);
  int wid = threadIdx.x>>6, lane = threadIdx.x&63;
  __syncthreads();
  if(lane==0) sm[wid]=v;
  __syncthreads();
  return sm[0]+sm[1]+sm[2]+sm[3];
}

// ---------------- D0: runtime input-dtype detection ----------------
// f32 word's bits[14:7]: for bf16-pair data = low bf16's exponent (concentrated
// in [110,140] for N(0,1)-scale data); for genuine f32 = mantissa bits (uniform).
__global__ void d0_detect(const void* __restrict__ x, float* __restrict__ ws){
  __shared__ int cnt;
  if(threadIdx.x==0) cnt=0;
  __syncthreads();
  unsigned w = ((const unsigned*)x)[(size_t)threadIdx.x*931 + 17];
  int e = (w>>7)&0xFF;
  if(e>=110 && e<=140) atomicAdd(&cnt,1);
  __syncthreads();
  if(threadIdx.x==0) ((int*)(ws+OFF_FLAG))[0] = (cnt<32) ? 1 : 0;  // 1 => f32 inputs
}

// ---------------- P0: init states / slabs ----------------
__global__ void p0_init(float* __restrict__ ws, const void* __restrict__ w1,
                        const void* __restrict__ w2, const void* __restrict__ ln){
  int f = ((const int*)(ws+OFF_FLAG))[0];
  size_t id = (size_t)blockIdx.x*blockDim.x + threadIdx.x;
  size_t stride = (size_t)gridDim.x*blockDim.x;
  for(size_t t=id; t<(size_t)STSZ; t+=stride){
    int e = (int)(t % (size_t)(I_*D_));
    ws[OFF_MW1+t] = ldin(w1,e,f);
    ws[OFF_MW2+t] = ldin(w2,e,f);
    ws[OFF_SW1+t] = 0.f; ws[OFF_SW2+t] = 0.f;
  }
  for(size_t t=id; t<(size_t)(B_*D_); t+=stride){
    ws[OFF_MLN+t] = ldin(ln,t % D_,f);
    ws[OFF_SLN+t] = 0.f;
  }
  for(size_t t=id; t<(size_t)(NC_*B_*SLABSTR); t+=stride) ws[OFF_SLAB+t]=0.f;
  int* tick = (int*)(ws + OFF_TICK);
  for(size_t t=id; t<64; t+=stride) tick[t]=0;
}

// ---------------- P1a: projections k,v,q = silu(x@W^T) ----------------
__global__ void __launch_bounds__(256) p1a(const void* __restrict__ x,
                    const void* __restrict__ wk,
                    const void* __restrict__ wv,
                    const void* __restrict__ wq,
                    float* __restrict__ ws){
  int f = ((const int*)(ws+OFF_FLAG))[0];
  int pid = blockIdx.z;
  const void* W = (pid==0)?wk:((pid==1)?wv:wq);
  float* outp = ws + ((pid==0)?OFF_K:((pid==1)?OFF_V:OFF_Q));
  int r0 = blockIdx.x*64, j0 = blockIdx.y*64;
  __shared__ float xa[64][33], wa[64][33];
  float acc[4][4]={};
  int tx = threadIdx.x & 15, ty = threadIdx.x >> 4;
  for(int k0=0;k0<512;k0+=32){
    for(int l=threadIdx.x;l<2048;l+=256){
      int rr=l>>5, kk=l&31;
      xa[rr][kk] = ldin(x,(size_t)(r0+rr)*512 + k0+kk,f);
      wa[rr][kk] = ldin(W,(size_t)(j0+rr)*512 + k0+kk,f);
    }
    __syncthreads();
    for(int kk=0;kk<32;kk++){
      float a4[4],b4[4];
      #pragma unroll
      for(int i=0;i<4;i++){ a4[i]=xa[ty*4+i][kk]; b4[i]=wa[tx*4+i][kk]; }
      #pragma unroll
      for(int i=0;i<4;i++)
        #pragma unroll
        for(int j=0;j<4;j++) acc[i][j] += a4[i]*b4[j];
    }
    __syncthreads();
  }
  for(int i=0;i<4;i++)for(int j=0;j<4;j++){
    int r=r0+ty*4+i, cc=j0+tx*4+j;
    float z=acc[i][j];
    outp[(size_t)r*512+cc] = z/(1.f+expf(-z));
  }
}

// ---------------- P1b: rms(k),rms(q), |k|^2, gates ----------------
__global__ void __launch_bounds__(256) p1b(const void* __restrict__ x,
                    const void* __restrict__ kn,
                    const void* __restrict__ qn,
                    const void* __restrict__ aw,
                    const void* __restrict__ tw,
                    const void* __restrict__ ew,
                    float* __restrict__ ws){
  int f = ((const int*)(ws+OFF_FLAG))[0];
  int tok = blockIdx.x; int tid = threadIdx.x;
  __shared__ float sm[8];
  float* krow = ws + OFF_K + (size_t)tok*512;
  float* qrow = ws + OFF_Q + (size_t)tok*512;
  float a = krow[tid], b = krow[tid+256];
  float ss = blockReduceSum(a*a+b*b, sm);
  float n = rsqrtf(ss*(1.f/512.f) + 1e-6f);
  float k1v = a*n*ldin(kn,tid,f);
  float k2v = b*n*ldin(kn,tid+256,f);
  krow[tid]=k1v; krow[tid+256]=k2v;
  float kn2 = blockReduceSum(k1v*k1v+k2v*k2v, sm);
  if(tid==0) ws[OFF_KN2+tok]=kn2;
  a = qrow[tid]; b = qrow[tid+256];
  ss = blockReduceSum(a*a+b*b, sm);
  n = rsqrtf(ss*(1.f/512.f)+1e-6f);
  qrow[tid]=a*n*ldin(qn,tid,f);
  qrow[tid+256]=b*n*ldin(qn,tid+256,f);
  float x1=ldin(x,(size_t)tok*512+tid,f), x2=ldin(x,(size_t)tok*512+tid+256,f);
  float td = blockReduceSum(x1*ldin(tw,tid,f) + x2*ldin(tw,tid+256,f), sm);
  float ad = blockReduceSum(x1*ldin(aw,tid,f) + x2*ldin(aw,tid+256,f), sm);
  float ed = blockReduceSum(x1*ldin(ew,tid,f) + x2*ldin(ew,tid+256,f), sm);
  if(tid==0){
    ws[OFF_TH+tok] = 0.01f/(1.f+expf(-td));
    ws[OFF_AL+tok] = 1.f/(1.f+expf(-ad));
    ws[OFF_ET+tok] = 1.f/(1.f+expf(-ed));
  }
}

// ---------------- K1: update W1 (+ln) with chunk c-1 grads, compute z1,h for chunk c ----------------
__global__ void __launch_bounds__(256) k1_w1(float* __restrict__ ws, int c){
  int b = blockIdx.y, bx = blockIdx.x, tid = threadIdx.x;
  __shared__ float sE[32], sC[32], scal[3];
  __shared__ float aE[16][32], aC[16][32];
  __shared__ float kp[32][65], kc[32][65], mlds[16][65];
  __shared__ float hred[32];
  if(c>0){
    const float* slab = ws + OFF_SLAB + ((long)(c-1)*B_ + b)*SLABSTR;
    if(tid<32){ sE[tid]=slab[128+tid]; sC[tid]=slab[160+tid]; }
    if(tid>=32 && tid<35) scal[tid-32]=slab[192+(tid-32)];
  }
  __syncthreads();
  float PE = c>0? scal[0]:1.f, PB = c>0? scal[1]:1.f, Q = c>0? scal[2]:0.f;
  if(bx==64){
    if(c>0){
      for(int d=tid; d<512; d+=256){
        float gE=0,gC=0;
        for(int u=0;u<32;u++){
          float dl = ws[OFF_DLN + ((size_t)(b*32+u))*512 + d];
          gE += sE[u]*dl; gC += sC[u]*dl;
        }
        size_t ix = OFF_SLN + (size_t)b*512 + d;
        float sv=ws[ix], mv=ws[ix + (OFF_MLN-OFF_SLN)];
        ws[ix] = PE*sv - gE;
        ws[ix + (OFF_MLN-OFF_SLN)] = PB*mv + Q*sv - gC;
      }
    }
    return;
  }
  int i0 = bx*16;
  if(c>0){
    for(int l=tid;l<512;l+=256){
      int r=l>>5, u=l&31;
      float dv = ws[OFF_DHP + ((size_t)(b*I_ + i0 + r))*32 + u];
      aE[r][u] = sE[u]*dv; aC[r][u] = sC[u]*dv;
    }
  }
  if(tid<32) hred[tid]=0.f;
  __syncthreads();
  int tx = tid & 63, ty = tid >> 6;
  int r2 = tid >> 4, t0 = (tid & 15)*2;
  float z0=0.f, z1v=0.f;
  for(int dt=0; dt<512; dt+=64){
    for(int l=tid;l<2048;l+=256){
      int u=l>>6, dd=l&63;
      if(c>0) kp[u][dd] = ws[OFF_K + ((size_t)(b*S_ + (c-1)*32 + u))*512 + dt + dd];
      if(c<16) kc[u][dd] = ws[OFF_K + ((size_t)(b*S_ + c*32 + u))*512 + dt + dd];
    }
    __syncthreads();
    #pragma unroll
    for(int rr=0;rr<4;rr++){
      int r = ty*4+rr;
      size_t ix = OFF_SW1 + ((size_t)(b*I_ + i0 + r))*512 + dt + tx;
      float sv = ws[ix], mv = ws[ix + STSZ];
      float nm;
      if(c>0){
        float gE=0,gC=0;
        #pragma unroll
        for(int u=0;u<32;u++){ float kv=kp[u][tx]; gE += aE[r][u]*kv; gC += aC[r][u]*kv; }
        float nsv = PE*sv - gE;
        nm = PB*mv + Q*sv - gC;
        ws[ix]=nsv; ws[ix+STSZ]=nm;
      } else nm = mv;
      if(c<16) mlds[r][tx]=nm;
    }
    __syncthreads();
    if(c<16){
      for(int dd=0;dd<64;dd++){
        float m = mlds[r2][dd];
        z0  += m*kc[t0][dd];
        z1v += m*kc[t0+1][dd];
      }
    }
    __syncthreads();
  }
  if(c<16){
    size_t zb = (size_t)(b*I_ + i0 + r2)*32;
    ws[OFF_Z1 + zb + t0] = z0; ws[OFF_Z1 + zb + t0+1] = z1v;
    float h0 = z0/(1.f+expf(-z0)), h1 = z1v/(1.f+expf(-z1v));
    float* hb = ws + OFF_H2 + (size_t)(c&1)*HSZ;
    hb[zb+t0]=h0; hb[zb+t0+1]=h1;
    atomicAdd(&hred[t0], h0*h0);
    atomicAdd(&hred[t0+1], h1*h1);
    __syncthreads();
    if(tid<32) atomicAdd(ws + OFF_SLAB + ((size_t)c*B_ + b)*SLABSTR + tid, hred[tid]);
  }
}

// ---------------- K2: update W2 with chunk c-1 grads, compute o = W2@h_c ----------------
__global__ void __launch_bounds__(256) k2_w2(float* __restrict__ ws, int c){
  int b = blockIdx.y, bx = blockIdx.x, tid = threadIdx.x;
  int d0 = bx*8;
  __shared__ float sE[32], sC[32], scal[3];
  __shared__ float aE[8][32], aC[8][32];
  __shared__ float hpl[32][65], hcl[64][33], m2l[8][65];
  if(c>0){
    const float* slab = ws + OFF_SLAB + ((long)(c-1)*B_+b)*SLABSTR;
    if(tid<32){ sE[tid]=slab[128+tid]; sC[tid]=slab[160+tid]; }
    if(tid>=32&&tid<35) scal[tid-32]=slab[192+tid-32];
    __syncthreads();
    {
      int r = tid>>5, u = tid&31;
      float dv = ws[OFF_DO + ((size_t)(b*32+u))*512 + d0 + r];
      aE[r][u] = sE[u]*dv; aC[r][u] = sC[u]*dv;
    }
  }
  __syncthreads();
  float PE = c>0?scal[0]:1.f, PB=c>0?scal[1]:1.f, Q=c>0?scal[2]:0.f;
  int tx = tid&63, ty = tid>>6;
  int r2 = tid>>5, tcol = tid&31;
  float oacc = 0.f;
  const float* hprev = ws + OFF_H2 + (size_t)((c-1)&1)*HSZ;
  const float* hcur  = ws + OFF_H2 + (size_t)(c&1)*HSZ;
  for(int it=0; it<16; it++){
    int i0 = it*64;
    for(int l=tid;l<2048;l+=256){
      int ii=l>>5, u=l&31;
      if(c>0) hpl[u][ii] = hprev[(size_t)(b*I_ + i0 + ii)*32 + u];
      if(c<16) hcl[ii][u] = hcur[(size_t)(b*I_ + i0 + ii)*32 + u];
    }
    __syncthreads();
    #pragma unroll
    for(int rr=0;rr<2;rr++){
      int r = ty*2+rr;
      size_t ix = OFF_SW2 + ((size_t)(b*D_ + d0 + r))*1024 + i0 + tx;
      float sv = ws[ix], mv = ws[ix+STSZ];
      float nm;
      if(c>0){
        float gE=0,gC=0;
        #pragma unroll
        for(int u=0;u<32;u++){ float hv=hpl[u][tx]; gE+=aE[r][u]*hv; gC+=aC[r][u]*hv; }
        float nsv = PE*sv-gE; nm = PB*mv + Q*sv - gC;
        ws[ix]=nsv; ws[ix+STSZ]=nm;
      } else nm=mv;
      if(c<16) m2l[r][tx]=nm;
    }
    __syncthreads();
    if(c<16){
      for(int ii=0;ii<64;ii++) oacc += m2l[r2][ii]*hcl[ii][tcol];
    }
    __syncthreads();
  }
  if(c<16) ws[OFF_OB + ((size_t)(b*32+tcol))*512 + d0 + r2] = oacc;
}

// ---------------- K3: per-token rms backward: u, do, dln, norms ----------------
__global__ void __launch_bounds__(256) k3_rms(float* __restrict__ ws, int c){
  int t = blockIdx.x, b = blockIdx.y, tid=threadIdx.x;
  __shared__ float sm[8];
  int tok = b*S_ + c*32 + t;
  const float* orow = ws + OFF_OB + ((size_t)(b*32+t))*512;
  const float* krow = ws + OFF_K + (size_t)tok*512;
  const float* vrow = ws + OFF_V + (size_t)tok*512;
  const float* lrow = ws + OFF_MLN + (size_t)b*512;
  float th = ws[OFF_TH + tok];
  float o1=orow[tid], o2=orow[tid+256];
  float mu = blockReduceSum(o1*o1+o2*o2, sm)*(1.f/512.f);
  float n = rsqrtf(mu + 1e-6f);
  float l1=lrow[tid], l2=lrow[tid+256];
  float k1=krow[tid], k2=krow[tid+256];
  float v1=vrow[tid], v2=vrow[tid+256];
  float c2 = 2.f*th*(1.f/512.f);
  float u1 = c2*(k1 + o1*n*l1 - v1);
  float u2 = c2*(k2 + o2*n*l2 - v2);
  float s1 = blockReduceSum(u1*l1*o1 + u2*l2*o2, sm);
  float dln1 = u1*o1*n, dln2v = u2*o2*n;
  float f = n*n*n*s1*(1.f/512.f);
  float do1 = n*l1*u1 - f*o1;
  float do2 = n*l2*u2 - f*o2;
  float don2 = blockReduceSum(do1*do1+do2*do2, sm);
  float dl2s = blockReduceSum(dln1*dln1+dln2v*dln2v, sm);
  float* dorow = ws + OFF_DO + ((size_t)(b*32+t))*512;
  float* dlrow = ws + OFF_DLN + ((size_t)(b*32+t))*512;
  dorow[tid]=do1; dorow[tid+256]=do2;
  dlrow[tid]=dln1; dlrow[tid+256]=dln2v;
  if(tid==0){
    float* slab = ws + OFF_SLAB + ((size_t)c*B_+b)*SLABSTR;
    slab[64+t]=don2; slab[96+t]=dl2s;
  }
}

// ---------------- K4: dh = W2^T do, dhp, grad-norm + scan scalars ----------------
__global__ void __launch_bounds__(256) k4_dh(float* __restrict__ ws, int c){
  int bx = blockIdx.x, b = blockIdx.y, tid = threadIdx.x;
  int i0 = bx*16;
  __shared__ float dol[32][65], m2t[64][17];
  __shared__ float red[32];
  __shared__ float coefl[32], bsufl[32];
  __shared__ int lastf;
  int r = tid>>5, tcol = tid&31;
  float dh0=0, dh1=0;
  for(int dt=0; dt<512; dt+=64){
    for(int l=tid;l<2048;l+=256){
      int t=l>>6, dd=l&63;
      dol[t][dd] = ws[OFF_DO + ((size_t)(b*32+t))*512 + dt+dd];
    }
    for(int l=tid;l<1024;l+=256){
      int dd=l>>4, ii=l&15;
      m2t[dd][ii] = ws[OFF_MW2 + ((size_t)(b*D_ + dt+dd))*1024 + i0 + ii];
    }
    __syncthreads();
    for(int dd=0;dd<64;dd++){
      float dv = dol[tcol][dd];
      dh0 += m2t[dd][r]*dv;
      dh1 += m2t[dd][r+8]*dv;
    }
    __syncthreads();
  }
  size_t zb0 = (size_t)(b*I_ + i0 + r)*32 + tcol;
  size_t zb1 = (size_t)(b*I_ + i0 + r + 8)*32 + tcol;
  float z0 = ws[OFF_Z1+zb0], z1v = ws[OFF_Z1+zb1];
  float s0 = 1.f/(1.f+expf(-z0)), s1g = 1.f/(1.f+expf(-z1v));
  float dp0 = dh0 * s0*(1.f + z0*(1.f-s0));
  float dp1 = dh1 * s1g*(1.f + z1v*(1.f-s1g));
  ws[OFF_DHP+zb0]=dp0; ws[OFF_DHP+zb1]=dp1;
  if(tid<32) red[tid]=0.f;
  __syncthreads();
  atomicAdd(&red[tcol], dp0*dp0+dp1*dp1);
  __syncthreads();
  float* slab = ws + OFF_SLAB + ((size_t)c*B_+b)*SLABSTR;
  if(tid<32) atomicAdd(&slab[32+tid], red[tid]);
  __threadfence();
  __syncthreads();
  if(tid==0){
    int* tick = (int*)(ws+OFF_TICK);
    lastf = (atomicAdd(&tick[c*B_+b],1) == 63) ? 1 : 0;
  }
  __syncthreads();
  if(!lastf) return;
  if(tid<32){
    int t = tid;
    float sqd = atomicAdd(&slab[32+t], 0.f);
    float hn  = atomicAdd(&slab[0+t], 0.f);
    float don2 = slab[64+t], dl2 = slab[96+t];
    float kn2 = ws[OFF_KN2 + b*S_ + c*32 + t];
    float sq = sqd*kn2 + don2*hn + dl2;
    coefl[t] = fminf(1.f/(sqrtf(sq)+1e-6f), 1.f);
  }
  __syncthreads();
  if(tid==0){
    const float* eta = ws + OFF_ET + b*S_ + c*32;
    const float* alp = ws + OFF_AL + b*S_ + c*32;
    float Esuf=1.f, Bsuf=1.f, cu=1.f;
    for(int u=31;u>=0;u--){
      if(u<31){
        float e1 = eta[u+1], b1 = 1.f-alp[u+1];
        Esuf *= e1; Bsuf *= b1;
        cu = Bsuf + e1*cu;
      }
      bsufl[u]=Bsuf;
      slab[128+u] = Esuf*coefl[u];
      slab[160+u] = cu*coefl[u];
    }
    float PE = Esuf*eta[0];
    float PB = Bsuf*(1.f-alp[0]);
    float Q=0.f, Epre=1.f;
    for(int t2=0;t2<32;t2++){ Epre *= eta[t2]; Q += bsufl[t2]*Epre; }
    slab[192]=PE; slab[193]=PB; slab[194]=Q;
  }
}

// ---------------- R1: hq = silu(q @ W1^T) ----------------
__global__ void __launch_bounds__(256) r1_gemm(float* __restrict__ ws){
  int b = blockIdx.z;
  int s0 = blockIdx.x*64, i0 = blockIdx.y*64;
  __shared__ float qa[64][33], wa[64][33];
  float acc[4][4]={};
  int tx = threadIdx.x&15, ty = threadIdx.x>>4;
  const float* qb = ws + OFF_Q + (size_t)b*S_*D_;
  const float* w1b = ws + OFF_MW1 + (size_t)b*I_*D_;
  for(int k0=0;k0<512;k0+=32){
    for(int l=threadIdx.x;l<2048;l+=256){
      int rr=l>>5, kk=l&31;
      qa[rr][kk] = qb[(size_t)(s0+rr)*512 + k0+kk];
      wa[rr][kk] = w1b[(size_t)(i0+rr)*512 + k0+kk];
    }
    __syncthreads();
    for(int kk=0;kk<32;kk++){
      float a4[4],b4[4];
      #pragma unroll
      for(int i=0;i<4;i++){a4[i]=qa[ty*4+i][kk]; b4[i]=wa[tx*4+i][kk];}
      #pragma unroll
      for(int i=0;i<4;i++)
        #pragma unroll
        for(int j=0;j<4;j++) acc[i][j]+=a4[i]*b4[j];
    }
    __syncthreads();
  }
  float* hq = ws + OFF_HQ + (size_t)b*S_*I_;
  for(int i=0;i<4;i++)for(int j=0;j<4;j++){
    int s=s0+ty*4+i, ii=i0+tx*4+j;
    float z=acc[i][j];
    hq[(size_t)s*1024 + ii] = z/(1.f+expf(-z));
  }
}

// ---------------- R2: oret = hq @ W2^T ----------------
__global__ void __launch_bounds__(256) r2_gemm(float* __restrict__ ws){
  int b=blockIdx.z;
  int s0=blockIdx.x*64, d0=blockIdx.y*64;
  __shared__ float ha[64][33], wa[64][33];
  float acc[4][4]={};
  int tx=threadIdx.x&15, ty=threadIdx.x>>4;
  const float* hq = ws + OFF_HQ + (size_t)b*S_*I_;
  const float* w2b = ws + OFF_MW2 + (size_t)b*D_*I_;
  for(int k0=0;k0<1024;k0+=32){
    for(int l=threadIdx.x;l<2048;l+=256){
      int rr=l>>5,kk=l&31;
      ha[rr][kk]=hq[(size_t)(s0+rr)*1024+k0+kk];
      wa[rr][kk]=w2b[(size_t)(d0+rr)*1024+k0+kk];
    }
    __syncthreads();
    for(int kk=0;kk<32;kk++){
      float a4[4],b4[4];
      #pragma unroll
      for(int i=0;i<4;i++){a4[i]=ha[ty*4+i][kk]; b4[i]=wa[tx*4+i][kk];}
      #pragma unroll
      for(int i=0;i<4;i++)
        #pragma unroll
        for(int j=0;j<4;j++)acc[i][j]+=a4[i]*b4[j];
    }
    __syncthreads();
  }
  float* od = ws + OFF_ORET + (size_t)b*S_*D_;
  for(int i=0;i<4;i++)for(int j=0;j<4;j++)
    od[(size_t)(s0+ty*4+i)*512 + d0+tx*4+j] = acc[i][j];
}

// ---------------- R3: out = q + rms(oret, Mln) ----------------
__global__ void __launch_bounds__(256) r3_out(float* __restrict__ ws, void* __restrict__ out){
  int f = ((const int*)(ws+OFF_FLAG))[0];
  int tok=blockIdx.x, tid=threadIdx.x;
  int b = tok >> 9;
  __shared__ float sm[8];
  const float* orow = ws + OFF_ORET + (size_t)tok*512;
  const float* qrow = ws + OFF_Q + (size_t)tok*512;
  const float* lrow = ws + OFF_MLN + (size_t)b*512;
  float o1=orow[tid], o2=orow[tid+256];
  float mu = blockReduceSum(o1*o1+o2*o2, sm)*(1.f/512.f);
  float n = rsqrtf(mu+1e-6f);
  float r1v = qrow[tid]     + o1*n*lrow[tid];
  float r2v = qrow[tid+256] + o2*n*lrow[tid+256];
  if(f){
    ((float*)out)[(size_t)tok*512+tid]     = r1v;
    ((float*)out)[(size_t)tok*512+tid+256] = r2v;
  } else {
    ((__hip_bfloat16*)out)[(size_t)tok*512+tid]     = __float2bfloat16(r1v);
    ((__hip_bfloat16*)out)[(size_t)tok*512+tid+256] = __float2bfloat16(r2v);
  }
}

extern "C" void kernel_launch(void* const* d_in, const int* in_sizes, int n_in,
                              void* d_out, int out_size, void* d_ws, size_t ws_size,
                              hipStream_t stream) {
  const void* x  = d_in[0];
  const void* wq = d_in[1];
  const void* wk = d_in[2];
  const void* wv = d_in[3];
  const void* qn = d_in[4];
  const void* kn = d_in[5];
  const void* aw = d_in[6];
  const void* tw = d_in[7];
  const void* ew = d_in[8];
  const void* w1 = d_in[9];
  const void* w2 = d_in[10];
  const void* ln = d_in[11];
  float* ws = (float*)d_ws;

  d0_detect<<<1,64,0,stream>>>(x, ws);
  p0_init<<<2048,256,0,stream>>>(ws, w1, w2, ln);
  p1a<<<dim3(32,8,3),256,0,stream>>>(x, wk, wv, wq, ws);
  p1b<<<2048,256,0,stream>>>(x, kn, qn, aw, tw, ew, ws);
  for(int c=0;c<=16;c++){
    k1_w1<<<dim3(65,4),256,0,stream>>>(ws, c);
    k2_w2<<<dim3(64,4),256,0,stream>>>(ws, c);
    if(c<16){
      k3_rms<<<dim3(32,4),256,0,stream>>>(ws, c);
      k4_dh<<<dim3(64,4),256,0,stream>>>(ws, c);
    }
  }
  r1_gemm<<<dim3(8,16,4),256,0,stream>>>(ws);
  r2_gemm<<<dim3(8,8,4),256,0,stream>>>(ws);
  r3_out<<<2048,256,0,stream>>>(ws, d_out);
}

// Round 3
// 1783.335 us; speedup vs baseline: 2.2650x; 2.2650x over previous
//
#include <hip/hip_runtime.h>
#include <hip/hip_bf16.h>

#define B_ 4
#define S_ 512
#define D_ 512
#define I_ 1024
#define C_ 32
#define NC_ 16

// ---- ws layout (float offsets) ----
#define KBUF (B_*S_*D_)
#define STSZ (B_*I_*D_)
#define HSZ  (B_*I_*C_)
#define DOSZ (B_*C_*D_)
#define OFF_K    0
#define OFF_V    (OFF_K + KBUF)
#define OFF_Q    (OFF_V + KBUF)
#define OFF_TH   (OFF_Q + KBUF)
#define OFF_AL   (OFF_TH + B_*S_)
#define OFF_ET   (OFF_AL + B_*S_)
#define OFF_KN2  (OFF_ET + B_*S_)
#define OFF_SW1  (OFF_KN2 + B_*S_)
#define OFF_MW1  (OFF_SW1 + STSZ)
#define OFF_SW2  (OFF_MW1 + STSZ)
#define OFF_MW2  (OFF_SW2 + STSZ)
#define OFF_SLN  (OFF_MW2 + STSZ)
#define OFF_MLN  (OFF_SLN + B_*D_)
#define OFF_H2   (OFF_MLN + B_*D_)
#define OFF_Z1   (OFF_H2 + 2*HSZ)
#define OFF_DHP  (OFF_Z1 + HSZ)
#define OFF_DO   (OFF_DHP + HSZ)
#define OFF_DLN  (OFF_DO + DOSZ)
#define OFF_OB   (OFF_DLN + DOSZ)
#define OFF_SLAB (OFF_OB + DOSZ)
#define SLABSTR  256
#define OFF_TICK (OFF_SLAB + NC_*B_*SLABSTR)
#define OFF_FLAG (OFF_TICK + 64)
// aliases (dead after chunk loop)
#define OFF_HQ   OFF_K
#define OFF_ORET OFF_SW1

__device__ __forceinline__ float bf2f(__hip_bfloat16 v){ return __bfloat162float(v); }
__device__ __forceinline__ float ldin(const void* p, size_t i, int f){
  return f ? ((const float*)p)[i] : bf2f(((const __hip_bfloat16*)p)[i]);
}
// vectorized dtype-branched load of 4 consecutive elements (i % 4 == 0)
__device__ __forceinline__ float4 ld4g(const void* p, size_t i, int f){
  if(f) return ((const float4*)p)[i>>2];
  ushort4 u = ((const ushort4*)p)[i>>2];
  float4 r;
  r.x = __uint_as_float(((unsigned)u.x)<<16);
  r.y = __uint_as_float(((unsigned)u.y)<<16);
  r.z = __uint_as_float(((unsigned)u.z)<<16);
  r.w = __uint_as_float(((unsigned)u.w)<<16);
  return r;
}

__device__ __forceinline__ float blockReduceSum(float v, float* sm){
  #pragma unroll
  for(int o=32;o>0;o>>=1) v += __shfl_down(v,o,64);
  int wid = threadIdx.x>>6, lane = threadIdx.x&63;
  __syncthreads();
  if(lane==0) sm[wid]=v;
  __syncthreads();
  return sm[0]+sm[1]+sm[2]+sm[3];
}

// ---------------- D0: runtime input-dtype detection ----------------
__global__ void d0_detect(const void* __restrict__ x, float* __restrict__ ws){
  __shared__ int cnt;
  if(threadIdx.x==0) cnt=0;
  __syncthreads();
  unsigned w = ((const unsigned*)x)[(size_t)threadIdx.x*931 + 17];
  int e = (w>>7)&0xFF;
  if(e>=110 && e<=140) atomicAdd(&cnt,1);
  __syncthreads();
  if(threadIdx.x==0) ((int*)(ws+OFF_FLAG))[0] = (cnt<32) ? 1 : 0;  // 1 => f32 inputs
}

// ---------------- P0: init states / slabs (f4) ----------------
__global__ void p0_init(float* __restrict__ ws, const void* __restrict__ w1,
                        const void* __restrict__ w2, const void* __restrict__ ln){
  int f = ((const int*)(ws+OFF_FLAG))[0];
  size_t id = (size_t)blockIdx.x*blockDim.x + threadIdx.x;
  size_t stride = (size_t)gridDim.x*blockDim.x;
  float4 z4 = {0.f,0.f,0.f,0.f};
  for(size_t t4=id; t4<(size_t)(STSZ/4); t4+=stride){
    size_t e4 = t4 % (size_t)(I_*D_/4);
    *(float4*)(ws+OFF_MW1+t4*4) = ld4g(w1, e4*4, f);
    *(float4*)(ws+OFF_MW2+t4*4) = ld4g(w2, e4*4, f);
    *(float4*)(ws+OFF_SW1+t4*4) = z4;
    *(float4*)(ws+OFF_SW2+t4*4) = z4;
  }
  for(size_t t=id; t<(size_t)(B_*D_); t+=stride){
    ws[OFF_MLN+t] = ldin(ln,t % D_,f);
    ws[OFF_SLN+t] = 0.f;
  }
  for(size_t t=id; t<(size_t)(NC_*B_*SLABSTR); t+=stride) ws[OFF_SLAB+t]=0.f;
  int* tick = (int*)(ws + OFF_TICK);
  for(size_t t=id; t<64; t+=stride) tick[t]=0;
}

// ---------------- P1a: k,v,q = silu(x@W^T), transposed-LDS f4 GEMM ----------------
__global__ void __launch_bounds__(256) p1a(const void* __restrict__ x,
                    const void* __restrict__ wk,
                    const void* __restrict__ wv,
                    const void* __restrict__ wq,
                    float* __restrict__ ws){
  int f = ((const int*)(ws+OFF_FLAG))[0];
  int pid = blockIdx.z;
  const void* W = (pid==0)?wk:((pid==1)?wv:wq);
  float* outp = ws + ((pid==0)?OFF_K:((pid==1)?OFF_V:OFF_Q));
  int r0 = blockIdx.x*64, j0 = blockIdx.y*64;
  __shared__ __align__(16) float xa[32][68], wa[32][68];
  float acc[4][4]={};
  int tx = threadIdx.x & 15, ty = threadIdx.x >> 4;
  for(int k0=0;k0<512;k0+=32){
    #pragma unroll
    for(int q=0;q<2;q++){
      int f4id = threadIdx.x + 256*q;       // 512 f4 per matrix
      int row = f4id>>3, kq = f4id&7;
      float4 v = ld4g(x, (size_t)(r0+row)*512 + k0 + kq*4, f);
      xa[kq*4+0][row]=v.x; xa[kq*4+1][row]=v.y; xa[kq*4+2][row]=v.z; xa[kq*4+3][row]=v.w;
      float4 w = ld4g(W, (size_t)(j0+row)*512 + k0 + kq*4, f);
      wa[kq*4+0][row]=w.x; wa[kq*4+1][row]=w.y; wa[kq*4+2][row]=w.z; wa[kq*4+3][row]=w.w;
    }
    __syncthreads();
    #pragma unroll
    for(int kk=0;kk<32;kk++){
      float4 a4 = *(float4*)&xa[kk][ty*4];
      float4 b4 = *(float4*)&wa[kk][tx*4];
      float a_[4]={a4.x,a4.y,a4.z,a4.w}, b_[4]={b4.x,b4.y,b4.z,b4.w};
      #pragma unroll
      for(int i=0;i<4;i++)
        #pragma unroll
        for(int j=0;j<4;j++) acc[i][j] += a_[i]*b_[j];
    }
    __syncthreads();
  }
  #pragma unroll
  for(int i=0;i<4;i++){
    float4 o4;
    float z0=acc[i][0], z1=acc[i][1], z2=acc[i][2], z3=acc[i][3];
    o4.x = z0/(1.f+expf(-z0)); o4.y = z1/(1.f+expf(-z1));
    o4.z = z2/(1.f+expf(-z2)); o4.w = z3/(1.f+expf(-z3));
    *(float4*)(outp + (size_t)(r0+ty*4+i)*512 + j0 + tx*4) = o4;
  }
}

// ---------------- P1b: rms(k),rms(q), |k|^2, gates ----------------
__global__ void __launch_bounds__(256) p1b(const void* __restrict__ x,
                    const void* __restrict__ kn,
                    const void* __restrict__ qn,
                    const void* __restrict__ aw,
                    const void* __restrict__ tw,
                    const void* __restrict__ ew,
                    float* __restrict__ ws){
  int f = ((const int*)(ws+OFF_FLAG))[0];
  int tok = blockIdx.x; int tid = threadIdx.x;
  __shared__ float sm[8];
  float* krow = ws + OFF_K + (size_t)tok*512;
  float* qrow = ws + OFF_Q + (size_t)tok*512;
  float a = krow[tid], b = krow[tid+256];
  float ss = blockReduceSum(a*a+b*b, sm);
  float n = rsqrtf(ss*(1.f/512.f) + 1e-6f);
  float k1v = a*n*ldin(kn,tid,f);
  float k2v = b*n*ldin(kn,tid+256,f);
  krow[tid]=k1v; krow[tid+256]=k2v;
  float kn2 = blockReduceSum(k1v*k1v+k2v*k2v, sm);
  if(tid==0) ws[OFF_KN2+tok]=kn2;
  a = qrow[tid]; b = qrow[tid+256];
  ss = blockReduceSum(a*a+b*b, sm);
  n = rsqrtf(ss*(1.f/512.f)+1e-6f);
  qrow[tid]=a*n*ldin(qn,tid,f);
  qrow[tid+256]=b*n*ldin(qn,tid+256,f);
  float x1=ldin(x,(size_t)tok*512+tid,f), x2=ldin(x,(size_t)tok*512+tid+256,f);
  float td = blockReduceSum(x1*ldin(tw,tid,f) + x2*ldin(tw,tid+256,f), sm);
  float ad = blockReduceSum(x1*ldin(aw,tid,f) + x2*ldin(aw,tid+256,f), sm);
  float ed = blockReduceSum(x1*ldin(ew,tid,f) + x2*ldin(ew,tid+256,f), sm);
  if(tid==0){
    ws[OFF_TH+tok] = 0.01f/(1.f+expf(-td));
    ws[OFF_AL+tok] = 1.f/(1.f+expf(-ad));
    ws[OFF_ET+tok] = 1.f/(1.f+expf(-ed));
  }
}

// ---------------- K1: update W1(+ln) w/ chunk c-1 grads; z1,h for chunk c ----------------
__global__ void __launch_bounds__(256) k1_w1(float* __restrict__ ws, int c){
  int b = blockIdx.y, bx = blockIdx.x, tid = threadIdx.x;
  __shared__ float sE[32], sC[32], scal[3];
  if(c>0){
    const float* slab = ws + OFF_SLAB + ((long)(c-1)*B_ + b)*SLABSTR;
    if(tid<32){ sE[tid]=slab[128+tid]; sC[tid]=slab[160+tid]; }
    if(tid>=32 && tid<35) scal[tid-32]=slab[192+(tid-32)];
  }
  __syncthreads();
  float PE = c>0? scal[0]:1.f, PB = c>0? scal[1]:1.f, Q = c>0? scal[2]:0.f;
  if(bx==128){
    if(c>0){
      for(int d=tid; d<512; d+=256){
        float gE=0,gC=0;
        for(int u=0;u<32;u++){
          float dl = ws[OFF_DLN + ((size_t)(b*32+u))*512 + d];
          gE += sE[u]*dl; gC += sC[u]*dl;
        }
        size_t ix = OFF_SLN + (size_t)b*512 + d;
        float sv=ws[ix], mv=ws[ix + (OFF_MLN-OFF_SLN)];
        ws[ix] = PE*sv - gE;
        ws[ix + (OFF_MLN-OFF_SLN)] = PB*mv + Q*sv - gC;
      }
    }
    return;
  }
  __shared__ __align__(16) float kp[32][132], kc[32][132], mt[8][132];
  __shared__ float aE[8][32], aC[8][32], hred[32];
  int i0 = bx*8;
  int r = tid>>5, l = tid&31;
  if(c>0){
    float dv = ws[OFF_DHP + ((size_t)(b*I_ + i0 + r))*32 + l];
    aE[r][l] = sE[l]*dv; aC[r][l] = sC[l]*dv;
  }
  if(tid<32) hred[tid]=0.f;
  float z = 0.f;
  const float* Kbase = ws + OFF_K + (size_t)b*S_*D_;
  for(int dt=0; dt<512; dt+=128){
    #pragma unroll
    for(int q=0;q<4;q++){
      int f4id = tid + 256*q;          // 1024 f4 per tile
      int u = f4id>>5, dq = f4id&31;
      if(c>0) *(float4*)&kp[u][dq*4] = *(const float4*)(Kbase + (size_t)((c-1)*32+u)*512 + dt + dq*4);
      if(c<16) *(float4*)&kc[u][dq*4] = *(const float4*)(Kbase + (size_t)(c*32+u)*512 + dt + dq*4);
    }
    __syncthreads();
    {
      size_t ix = OFF_SW1 + ((size_t)(b*I_ + i0 + r))*512 + dt + l*4;
      float4 nm;
      if(c>0){
        float4 sv = *(float4*)(ws+ix);
        float4 mv = *(float4*)(ws+ix+STSZ);
        float4 gE={0,0,0,0}, gC={0,0,0,0};
        #pragma unroll
        for(int u=0;u<32;u++){
          float4 kv = *(float4*)&kp[u][l*4];
          float ae = aE[r][u], ac = aC[r][u];
          gE.x += ae*kv.x; gE.y += ae*kv.y; gE.z += ae*kv.z; gE.w += ae*kv.w;
          gC.x += ac*kv.x; gC.y += ac*kv.y; gC.z += ac*kv.z; gC.w += ac*kv.w;
        }
        float4 ns;
        ns.x = PE*sv.x - gE.x; ns.y = PE*sv.y - gE.y; ns.z = PE*sv.z - gE.z; ns.w = PE*sv.w - gE.w;
        nm.x = PB*mv.x + Q*sv.x - gC.x; nm.y = PB*mv.y + Q*sv.y - gC.y;
        nm.z = PB*mv.z + Q*sv.z - gC.z; nm.w = PB*mv.w + Q*sv.w - gC.w;
        *(float4*)(ws+ix) = ns;
        *(float4*)(ws+ix+STSZ) = nm;
      } else {
        nm = *(float4*)(ws+ix+STSZ);
      }
      *(float4*)&mt[r][l*4] = nm;
    }
    __syncthreads();
    if(c<16){
      #pragma unroll
      for(int d4=0; d4<32; d4++){
        float4 m4 = *(float4*)&mt[r][d4*4];
        float4 k4 = *(float4*)&kc[l][d4*4];     // l = token
        z += m4.x*k4.x + m4.y*k4.y + m4.z*k4.z + m4.w*k4.w;
      }
    }
    __syncthreads();
  }
  if(c<16){
    size_t zb = (size_t)(b*I_ + i0 + r)*32 + l;
    ws[OFF_Z1 + zb] = z;
    float h = z/(1.f+expf(-z));
    (ws + OFF_H2 + (size_t)(c&1)*HSZ)[zb] = h;
    atomicAdd(&hred[l], h*h);
    __syncthreads();
    if(tid<32) atomicAdd(ws + OFF_SLAB + ((size_t)c*B_ + b)*SLABSTR + tid, hred[tid]);
  }
}

// ---------------- K2: update W2 w/ chunk c-1 grads; o = M2@h_c ----------------
__global__ void __launch_bounds__(256) k2_w2(float* __restrict__ ws, int c){
  int b = blockIdx.y, bx = blockIdx.x, tid = threadIdx.x;
  int d0 = bx*8;
  __shared__ float sE[32], sC[32], scal[3];
  __shared__ __align__(16) float hp[32][132], hc[32][132], mt2[8][132];
  __shared__ float aE[8][32], aC[8][32];
  int r = tid>>5, l = tid&31;
  if(c>0){
    const float* slab = ws + OFF_SLAB + ((long)(c-1)*B_+b)*SLABSTR;
    if(tid<32){ sE[tid]=slab[128+tid]; sC[tid]=slab[160+tid]; }
    if(tid>=32&&tid<35) scal[tid-32]=slab[192+tid-32];
    __syncthreads();
    float dv = ws[OFF_DO + ((size_t)(b*32+l))*512 + d0 + r];
    aE[r][l] = sE[l]*dv; aC[r][l] = sC[l]*dv;
  }
  __syncthreads();
  float PE = c>0?scal[0]:1.f, PB=c>0?scal[1]:1.f, Q=c>0?scal[2]:0.f;
  float o = 0.f;
  const float* hprev = ws + OFF_H2 + (size_t)((c-1)&1)*HSZ;
  const float* hcur  = ws + OFF_H2 + (size_t)(c&1)*HSZ;
  for(int it=0; it<1024; it+=128){
    #pragma unroll
    for(int q=0;q<4;q++){
      int f4id = tid + 256*q;          // 1024 f4: ii=f4id>>3 (128), tq=f4id&7
      int ii = f4id>>3, tq = f4id&7;
      if(c>0){
        float4 v = *(const float4*)(hprev + (size_t)(b*I_+it+ii)*32 + tq*4);
        hp[tq*4+0][ii]=v.x; hp[tq*4+1][ii]=v.y; hp[tq*4+2][ii]=v.z; hp[tq*4+3][ii]=v.w;
      }
      if(c<16){
        float4 v = *(const float4*)(hcur + (size_t)(b*I_+it+ii)*32 + tq*4);
        hc[tq*4+0][ii]=v.x; hc[tq*4+1][ii]=v.y; hc[tq*4+2][ii]=v.z; hc[tq*4+3][ii]=v.w;
      }
    }
    __syncthreads();
    {
      size_t ix = OFF_SW2 + ((size_t)(b*D_ + d0 + r))*1024 + it + l*4;
      float4 nm;
      if(c>0){
        float4 sv = *(float4*)(ws+ix);
        float4 mv = *(float4*)(ws+ix+STSZ);
        float4 gE={0,0,0,0}, gC={0,0,0,0};
        #pragma unroll
        for(int u=0;u<32;u++){
          float4 hv = *(float4*)&hp[u][l*4];
          float ae = aE[r][u], ac = aC[r][u];
          gE.x += ae*hv.x; gE.y += ae*hv.y; gE.z += ae*hv.z; gE.w += ae*hv.w;
          gC.x += ac*hv.x; gC.y += ac*hv.y; gC.z += ac*hv.z; gC.w += ac*hv.w;
        }
        float4 ns;
        ns.x = PE*sv.x - gE.x; ns.y = PE*sv.y - gE.y; ns.z = PE*sv.z - gE.z; ns.w = PE*sv.w - gE.w;
        nm.x = PB*mv.x + Q*sv.x - gC.x; nm.y = PB*mv.y + Q*sv.y - gC.y;
        nm.z = PB*mv.z + Q*sv.z - gC.z; nm.w = PB*mv.w + Q*sv.w - gC.w;
        *(float4*)(ws+ix) = ns;
        *(float4*)(ws+ix+STSZ) = nm;
      } else {
        nm = *(float4*)(ws+ix+STSZ);
      }
      *(float4*)&mt2[r][l*4] = nm;
    }
    __syncthreads();
    if(c<16){
      #pragma unroll
      for(int i4=0;i4<32;i4++){
        float4 m4 = *(float4*)&mt2[r][i4*4];
        float4 h4 = *(float4*)&hc[l][i4*4];   // l = token
        o += m4.x*h4.x + m4.y*h4.y + m4.z*h4.z + m4.w*h4.w;
      }
    }
    __syncthreads();
  }
  if(c<16) ws[OFF_OB + ((size_t)(b*32+l))*512 + d0 + r] = o;
}

// ---------------- K3: per-token rms backward ----------------
__global__ void __launch_bounds__(256) k3_rms(float* __restrict__ ws, int c){
  int t = blockIdx.x, b = blockIdx.y, tid=threadIdx.x;
  __shared__ float sm[8];
  int tok = b*S_ + c*32 + t;
  const float* orow = ws + OFF_OB + ((size_t)(b*32+t))*512;
  const float* krow = ws + OFF_K + (size_t)tok*512;
  const float* vrow = ws + OFF_V + (size_t)tok*512;
  const float* lrow = ws + OFF_MLN + (size_t)b*512;
  float th = ws[OFF_TH + tok];
  float o1=orow[tid], o2=orow[tid+256];
  float mu = blockReduceSum(o1*o1+o2*o2, sm)*(1.f/512.f);
  float n = rsqrtf(mu + 1e-6f);
  float l1=lrow[tid], l2=lrow[tid+256];
  float k1=krow[tid], k2=krow[tid+256];
  float v1=vrow[tid], v2=vrow[tid+256];
  float c2 = 2.f*th*(1.f/512.f);
  float u1 = c2*(k1 + o1*n*l1 - v1);
  float u2 = c2*(k2 + o2*n*l2 - v2);
  float s1 = blockReduceSum(u1*l1*o1 + u2*l2*o2, sm);
  float dln1 = u1*o1*n, dln2v = u2*o2*n;
  float f = n*n*n*s1*(1.f/512.f);
  float do1 = n*l1*u1 - f*o1;
  float do2 = n*l2*u2 - f*o2;
  float don2 = blockReduceSum(do1*do1+do2*do2, sm);
  float dl2s = blockReduceSum(dln1*dln1+dln2v*dln2v, sm);
  float* dorow = ws + OFF_DO + ((size_t)(b*32+t))*512;
  float* dlrow = ws + OFF_DLN + ((size_t)(b*32+t))*512;
  dorow[tid]=do1; dorow[tid+256]=do2;
  dlrow[tid]=dln1; dlrow[tid+256]=dln2v;
  if(tid==0){
    float* slab = ws + OFF_SLAB + ((size_t)c*B_+b)*SLABSTR;
    slab[64+t]=don2; slab[96+t]=dl2s;
  }
}

// ---------------- K4: dh = M2^T do, dhp, grad-norm + scan scalars ----------------
__global__ void __launch_bounds__(256) k4_dh(float* __restrict__ ws, int c){
  int bx = blockIdx.x, b = blockIdx.y, tid = threadIdx.x;
  int i0 = bx*16;
  __shared__ __align__(16) float dol[32][132], m2[16][132];
  __shared__ float red[32], coefl[32], bsufl[32];
  __shared__ int lastf;
  int r = tid>>5, t = tid&31;
  float dh0=0, dh1=0;
  for(int dt=0; dt<512; dt+=128){
    #pragma unroll
    for(int q=0;q<4;q++){
      int f4id = tid + 256*q;        // 1024 f4: tt = f4id>>5, dq = f4id&31
      int tt = f4id>>5, dq = f4id&31;
      *(float4*)&dol[tt][dq*4] = *(const float4*)(ws + OFF_DO + (size_t)(b*32+tt)*512 + dt + dq*4);
    }
    #pragma unroll
    for(int q=0;q<2;q++){
      int f4id = tid + 256*q;        // 512 f4: dd = f4id>>2, iq = f4id&3
      int dd = f4id>>2, iq = f4id&3;
      float4 v = *(const float4*)(ws + OFF_MW2 + (size_t)(b*D_+dt+dd)*1024 + i0 + iq*4);
      m2[iq*4+0][dd]=v.x; m2[iq*4+1][dd]=v.y; m2[iq*4+2][dd]=v.z; m2[iq*4+3][dd]=v.w;
    }
    __syncthreads();
    #pragma unroll
    for(int d4=0; d4<32; d4++){
      float4 dv = *(float4*)&dol[t][d4*4];
      float4 ma = *(float4*)&m2[r][d4*4];
      float4 mb = *(float4*)&m2[r+8][d4*4];
      dh0 += ma.x*dv.x + ma.y*dv.y + ma.z*dv.z + ma.w*dv.w;
      dh1 += mb.x*dv.x + mb.y*dv.y + mb.z*dv.z + mb.w*dv.w;
    }
    __syncthreads();
  }
  size_t zb0 = (size_t)(b*I_ + i0 + r)*32 + t;
  size_t zb1 = (size_t)(b*I_ + i0 + r + 8)*32 + t;
  float z0 = ws[OFF_Z1+zb0], z1v = ws[OFF_Z1+zb1];
  float s0 = 1.f/(1.f+expf(-z0)), s1g = 1.f/(1.f+expf(-z1v));
  float dp0 = dh0 * s0*(1.f + z0*(1.f-s0));
  float dp1 = dh1 * s1g*(1.f + z1v*(1.f-s1g));
  ws[OFF_DHP+zb0]=dp0; ws[OFF_DHP+zb1]=dp1;
  if(tid<32) red[tid]=0.f;
  __syncthreads();
  atomicAdd(&red[t], dp0*dp0+dp1*dp1);
  __syncthreads();
  float* slab = ws + OFF_SLAB + ((size_t)c*B_+b)*SLABSTR;
  if(tid<32) atomicAdd(&slab[32+tid], red[tid]);
  __threadfence();
  __syncthreads();
  if(tid==0){
    int* tick = (int*)(ws+OFF_TICK);
    lastf = (atomicAdd(&tick[c*B_+b],1) == 63) ? 1 : 0;
  }
  __syncthreads();
  if(!lastf) return;
  if(tid<32){
    float sqd = atomicAdd(&slab[32+tid], 0.f);
    float hn  = atomicAdd(&slab[0+tid], 0.f);
    float don2 = slab[64+tid], dl2 = slab[96+tid];
    float kn2 = ws[OFF_KN2 + b*S_ + c*32 + tid];
    float sq = sqd*kn2 + don2*hn + dl2;
    coefl[tid] = fminf(1.f/(sqrtf(sq)+1e-6f), 1.f);
  }
  __syncthreads();
  if(tid==0){
    const float* eta = ws + OFF_ET + b*S_ + c*32;
    const float* alp = ws + OFF_AL + b*S_ + c*32;
    float Esuf=1.f, Bsuf=1.f, cu=1.f;
    for(int u=31;u>=0;u--){
      if(u<31){
        float e1 = eta[u+1], b1 = 1.f-alp[u+1];
        Esuf *= e1; Bsuf *= b1;
        cu = Bsuf + e1*cu;
      }
      bsufl[u]=Bsuf;
      slab[128+u] = Esuf*coefl[u];
      slab[160+u] = cu*coefl[u];
    }
    float PE = Esuf*eta[0];
    float PB = Bsuf*(1.f-alp[0]);
    float Q=0.f, Epre=1.f;
    for(int t2=0;t2<32;t2++){ Epre *= eta[t2]; Q += bsufl[t2]*Epre; }
    slab[192]=PE; slab[193]=PB; slab[194]=Q;
  }
}

// ---------------- R1: hq = silu(q @ M1^T) ----------------
__global__ void __launch_bounds__(256) r1_gemm(float* __restrict__ ws){
  int b = blockIdx.z;
  int s0 = blockIdx.x*64, i0 = blockIdx.y*64;
  __shared__ __align__(16) float qa[32][68], wa[32][68];
  float acc[4][4]={};
  int tx = threadIdx.x&15, ty = threadIdx.x>>4;
  const float* qb = ws + OFF_Q + (size_t)b*S_*D_;
  const float* w1b = ws + OFF_MW1 + (size_t)b*I_*D_;
  for(int k0=0;k0<512;k0+=32){
    #pragma unroll
    for(int q=0;q<2;q++){
      int f4id = threadIdx.x + 256*q;
      int row = f4id>>3, kq = f4id&7;
      float4 v = *(const float4*)(qb + (size_t)(s0+row)*512 + k0 + kq*4);
      qa[kq*4+0][row]=v.x; qa[kq*4+1][row]=v.y; qa[kq*4+2][row]=v.z; qa[kq*4+3][row]=v.w;
      float4 w = *(const float4*)(w1b + (size_t)(i0+row)*512 + k0 + kq*4);
      wa[kq*4+0][row]=w.x; wa[kq*4+1][row]=w.y; wa[kq*4+2][row]=w.z; wa[kq*4+3][row]=w.w;
    }
    __syncthreads();
    #pragma unroll
    for(int kk=0;kk<32;kk++){
      float4 a4 = *(float4*)&qa[kk][ty*4];
      float4 b4 = *(float4*)&wa[kk][tx*4];
      float a_[4]={a4.x,a4.y,a4.z,a4.w}, b_[4]={b4.x,b4.y,b4.z,b4.w};
      #pragma unroll
      for(int i=0;i<4;i++)
        #pragma unroll
        for(int j=0;j<4;j++) acc[i][j]+=a_[i]*b_[j];
    }
    __syncthreads();
  }
  float* hq = ws + OFF_HQ + (size_t)b*S_*I_;
  #pragma unroll
  for(int i=0;i<4;i++){
    float4 o4;
    o4.x = acc[i][0]/(1.f+expf(-acc[i][0])); o4.y = acc[i][1]/(1.f+expf(-acc[i][1]));
    o4.z = acc[i][2]/(1.f+expf(-acc[i][2])); o4.w = acc[i][3]/(1.f+expf(-acc[i][3]));
    *(float4*)(hq + (size_t)(s0+ty*4+i)*1024 + i0 + tx*4) = o4;
  }
}

// ---------------- R2: oret = hq @ M2^T ----------------
__global__ void __launch_bounds__(256) r2_gemm(float* __restrict__ ws){
  int b=blockIdx.z;
  int s0=blockIdx.x*64, d0=blockIdx.y*64;
  __shared__ __align__(16) float ha[32][68], wa[32][68];
  float acc[4][4]={};
  int tx=threadIdx.x&15, ty=threadIdx.x>>4;
  const float* hq = ws + OFF_HQ + (size_t)b*S_*I_;
  const float* w2b = ws + OFF_MW2 + (size_t)b*D_*I_;
  for(int k0=0;k0<1024;k0+=32){
    #pragma unroll
    for(int q=0;q<2;q++){
      int f4id = threadIdx.x + 256*q;
      int row = f4id>>3, kq = f4id&7;
      float4 v = *(const float4*)(hq + (size_t)(s0+row)*1024 + k0 + kq*4);
      ha[kq*4+0][row]=v.x; ha[kq*4+1][row]=v.y; ha[kq*4+2][row]=v.z; ha[kq*4+3][row]=v.w;
      float4 w = *(const float4*)(w2b + (size_t)(d0+row)*1024 + k0 + kq*4);
      wa[kq*4+0][row]=w.x; wa[kq*4+1][row]=w.y; wa[kq*4+2][row]=w.z; wa[kq*4+3][row]=w.w;
    }
    __syncthreads();
    #pragma unroll
    for(int kk=0;kk<32;kk++){
      float4 a4 = *(float4*)&ha[kk][ty*4];
      float4 b4 = *(float4*)&wa[kk][tx*4];
      float a_[4]={a4.x,a4.y,a4.z,a4.w}, b_[4]={b4.x,b4.y,b4.z,b4.w};
      #pragma unroll
      for(int i=0;i<4;i++)
        #pragma unroll
        for(int j=0;j<4;j++) acc[i][j]+=a_[i]*b_[j];
    }
    __syncthreads();
  }
  float* od = ws + OFF_ORET + (size_t)b*S_*D_;
  #pragma unroll
  for(int i=0;i<4;i++){
    float4 o4 = {acc[i][0],acc[i][1],acc[i][2],acc[i][3]};
    *(float4*)(od + (size_t)(s0+ty*4+i)*512 + d0 + tx*4) = o4;
  }
}

// ---------------- R3: out = q + rms(oret, Mln) ----------------
__global__ void __launch_bounds__(256) r3_out(float* __restrict__ ws, void* __restrict__ out){
  int f = ((const int*)(ws+OFF_FLAG))[0];
  int tok=blockIdx.x, tid=threadIdx.x;
  int b = tok >> 9;
  __shared__ float sm[8];
  const float* orow = ws + OFF_ORET + (size_t)tok*512;
  const float* qrow = ws + OFF_Q + (size_t)tok*512;
  const float* lrow = ws + OFF_MLN + (size_t)b*512;
  float o1=orow[tid], o2=orow[tid+256];
  float mu = blockReduceSum(o1*o1+o2*o2, sm)*(1.f/512.f);
  float n = rsqrtf(mu+1e-6f);
  float r1v = qrow[tid]     + o1*n*lrow[tid];
  float r2v = qrow[tid+256] + o2*n*lrow[tid+256];
  if(f){
    ((float*)out)[(size_t)tok*512+tid]     = r1v;
    ((float*)out)[(size_t)tok*512+tid+256] = r2v;
  } else {
    ((__hip_bfloat16*)out)[(size_t)tok*512+tid]     = __float2bfloat16(r1v);
    ((__hip_bfloat16*)out)[(size_t)tok*512+tid+256] = __float2bfloat16(r2v);
  }
}

extern "C" void kernel_launch(void* const* d_in, const int* in_sizes, int n_in,
                              void* d_out, int out_size, void* d_ws, size_t ws_size,
                              hipStream_t stream) {
  const void* x  = d_in[0];
  const void* wq = d_in[1];
  const void* wk = d_in[2];
  const void* wv = d_in[3];
  const void* qn = d_in[4];
  const void* kn = d_in[5];
  const void* aw = d_in[6];
  const void* tw = d_in[7];
  const void* ew = d_in[8];
  const void* w1 = d_in[9];
  const void* w2 = d_in[10];
  const void* ln = d_in[11];
  float* ws = (float*)d_ws;

  d0_detect<<<1,64,0,stream>>>(x, ws);
  p0_init<<<2048,256,0,stream>>>(ws, w1, w2, ln);
  p1a<<<dim3(32,8,3),256,0,stream>>>(x, wk, wv, wq, ws);
  p1b<<<2048,256,0,stream>>>(x, kn, qn, aw, tw, ew, ws);
  for(int c=0;c<=16;c++){
    k1_w1<<<dim3(129,4),256,0,stream>>>(ws, c);
    k2_w2<<<dim3(64,4),256,0,stream>>>(ws, c);
    if(c<16){
      k3_rms<<<dim3(32,4),256,0,stream>>>(ws, c);
      k4_dh<<<dim3(64,4),256,0,stream>>>(ws, c);
    }
  }
  r1_gemm<<<dim3(8,16,4),256,0,stream>>>(ws);
  r2_gemm<<<dim3(8,8,4),256,0,stream>>>(ws);
  r3_out<<<2048,256,0,stream>>>(ws, d_out);
}

// Round 5
// 1783.312 us; speedup vs baseline: 2.2651x; 1.0000x over previous
//
#include <hip/hip_runtime.h>
#include <hip/hip_bf16.h>

#define B_ 4
#define S_ 512
#define D_ 512
#define I_ 1024
#define C_ 32
#define NC_ 16

// ---- ws layout (float offsets) ----
#define KBUF (B_*S_*D_)
#define STSZ (B_*I_*D_)
#define HSZ  (B_*I_*C_)
#define DOSZ (B_*C_*D_)
#define OFF_K    0
#define OFF_V    (OFF_K + KBUF)
#define OFF_Q    (OFF_V + KBUF)
#define OFF_TH   (OFF_Q + KBUF)
#define OFF_AL   (OFF_TH + B_*S_)
#define OFF_ET   (OFF_AL + B_*S_)
#define OFF_KN2  (OFF_ET + B_*S_)
#define OFF_SLN  (OFF_KN2 + B_*S_)
#define OFF_MLN  (OFF_SLN + B_*D_)
#define OFF_H2   (OFF_MLN + B_*D_)
#define OFF_Z1   (OFF_H2 + 2*HSZ)
#define OFF_DHP  (OFF_Z1 + HSZ)
#define OFF_DO   (OFF_DHP + HSZ)
#define OFF_DLN  (OFF_DO + DOSZ)
#define OFF_OB   (OFF_DLN + DOSZ)
#define OFF_SLAB (OFF_OB + DOSZ)
#define SLABSTR  256
#define OFF_TICK (OFF_SLAB + NC_*B_*SLABSTR)
#define OFF_FLAG (OFF_TICK + 64)
#define OFF_ORET (OFF_FLAG + 16)
#define OFF_BST  (OFF_ORET + KBUF)     // bf16 states start here (ushort*)
// bf16 state arrays (ushort element offsets within bst):
//   BSW1 = 0, BMW1 = STSZ, BSW2 = 2*STSZ, BMW2 = 3*STSZ
// alias (dead after chunk loop)
#define OFF_HQ   OFF_K

__device__ __forceinline__ float bf2f(__hip_bfloat16 v){ return __bfloat162float(v); }
__device__ __forceinline__ float bfu2f(unsigned short u){ return __uint_as_float(((unsigned)u)<<16); }
__device__ __forceinline__ unsigned short f2bfu(float f){
  unsigned x = __float_as_uint(f);
  return (unsigned short)((x + 0x7FFFu + ((x>>16)&1u)) >> 16);
}
__device__ __forceinline__ float4 u42f4(ushort4 u){
  float4 r; r.x=bfu2f(u.x); r.y=bfu2f(u.y); r.z=bfu2f(u.z); r.w=bfu2f(u.w); return r;
}
__device__ __forceinline__ ushort4 f42u4(float4 v){
  ushort4 r; r.x=f2bfu(v.x); r.y=f2bfu(v.y); r.z=f2bfu(v.z); r.w=f2bfu(v.w); return r;
}
__device__ __forceinline__ float ldin(const void* p, size_t i, int f){
  return f ? ((const float*)p)[i] : bf2f(((const __hip_bfloat16*)p)[i]);
}
__device__ __forceinline__ float4 ld4g(const void* p, size_t i, int f){
  if(f) return ((const float4*)p)[i>>2];
  return u42f4(((const ushort4*)p)[i>>2]);
}

__device__ __forceinline__ float blockReduceSum(float v, float* sm){
  #pragma unroll
  for(int o=32;o>0;o>>=1) v += __shfl_down(v,o,64);
  int wid = threadIdx.x>>6, lane = threadIdx.x&63;
  __syncthreads();
  if(lane==0) sm[wid]=v;
  __syncthreads();
  return sm[0]+sm[1]+sm[2]+sm[3];
}

// ---------------- D0: runtime input-dtype detection ----------------
__global__ void d0_detect(const void* __restrict__ x, float* __restrict__ ws){
  __shared__ int cnt;
  if(threadIdx.x==0) cnt=0;
  __syncthreads();
  unsigned w = ((const unsigned*)x)[(size_t)threadIdx.x*931 + 17];
  int e = (w>>7)&0xFF;
  if(e>=110 && e<=140) atomicAdd(&cnt,1);
  __syncthreads();
  if(threadIdx.x==0) ((int*)(ws+OFF_FLAG))[0] = (cnt<32) ? 1 : 0;  // 1 => f32 inputs
}

// ---------------- P0: init states / slabs ----------------
__global__ void p0_init(float* __restrict__ ws, const void* __restrict__ w1,
                        const void* __restrict__ w2, const void* __restrict__ ln){
  int f = ((const int*)(ws+OFF_FLAG))[0];
  unsigned short* bst = (unsigned short*)(ws + OFF_BST);
  size_t id = (size_t)blockIdx.x*blockDim.x + threadIdx.x;
  size_t stride = (size_t)gridDim.x*blockDim.x;
  ushort4 z4 = {0,0,0,0};
  for(size_t t4=id; t4<(size_t)(STSZ/4); t4+=stride){
    size_t e4 = t4 % (size_t)(I_*D_/4);
    *(ushort4*)(bst + (size_t)STSZ + t4*4)   = f42u4(ld4g(w1, e4*4, f));  // BMW1
    *(ushort4*)(bst + (size_t)3*STSZ + t4*4) = f42u4(ld4g(w2, e4*4, f));  // BMW2
    *(ushort4*)(bst + t4*4) = z4;                                          // BSW1
    *(ushort4*)(bst + (size_t)2*STSZ + t4*4) = z4;                         // BSW2
  }
  for(size_t t=id; t<(size_t)(B_*D_); t+=stride){
    ws[OFF_MLN+t] = ldin(ln,t % D_,f);
    ws[OFF_SLN+t] = 0.f;
  }
  for(size_t t=id; t<(size_t)(NC_*B_*SLABSTR); t+=stride) ws[OFF_SLAB+t]=0.f;
  int* tick = (int*)(ws + OFF_TICK);
  for(size_t t=id; t<64; t+=stride) tick[t]=0;
}

// ---------------- P1a: k,v,q = silu(x@W^T) ----------------
__global__ void __launch_bounds__(256) p1a(const void* __restrict__ x,
                    const void* __restrict__ wk,
                    const void* __restrict__ wv,
                    const void* __restrict__ wq,
                    float* __restrict__ ws){
  int f = ((const int*)(ws+OFF_FLAG))[0];
  int pid = blockIdx.z;
  const void* W = (pid==0)?wk:((pid==1)?wv:wq);
  float* outp = ws + ((pid==0)?OFF_K:((pid==1)?OFF_V:OFF_Q));
  int r0 = blockIdx.x*64, j0 = blockIdx.y*64;
  __shared__ __align__(16) float xa[32][68], wa[32][68];
  float acc[4][4]={};
  int tx = threadIdx.x & 15, ty = threadIdx.x >> 4;
  for(int k0=0;k0<512;k0+=32){
    #pragma unroll
    for(int q=0;q<2;q++){
      int f4id = threadIdx.x + 256*q;
      int row = f4id>>3, kq = f4id&7;
      float4 v = ld4g(x, (size_t)(r0+row)*512 + k0 + kq*4, f);
      xa[kq*4+0][row]=v.x; xa[kq*4+1][row]=v.y; xa[kq*4+2][row]=v.z; xa[kq*4+3][row]=v.w;
      float4 w = ld4g(W, (size_t)(j0+row)*512 + k0 + kq*4, f);
      wa[kq*4+0][row]=w.x; wa[kq*4+1][row]=w.y; wa[kq*4+2][row]=w.z; wa[kq*4+3][row]=w.w;
    }
    __syncthreads();
    #pragma unroll
    for(int kk=0;kk<32;kk++){
      float4 a4 = *(float4*)&xa[kk][ty*4];
      float4 b4 = *(float4*)&wa[kk][tx*4];
      float a_[4]={a4.x,a4.y,a4.z,a4.w}, b_[4]={b4.x,b4.y,b4.z,b4.w};
      #pragma unroll
      for(int i=0;i<4;i++)
        #pragma unroll
        for(int j=0;j<4;j++) acc[i][j] += a_[i]*b_[j];
    }
    __syncthreads();
  }
  #pragma unroll
  for(int i=0;i<4;i++){
    float4 o4;
    float z0=acc[i][0], z1=acc[i][1], z2=acc[i][2], z3=acc[i][3];
    o4.x = z0/(1.f+expf(-z0)); o4.y = z1/(1.f+expf(-z1));
    o4.z = z2/(1.f+expf(-z2)); o4.w = z3/(1.f+expf(-z3));
    *(float4*)(outp + (size_t)(r0+ty*4+i)*512 + j0 + tx*4) = o4;
  }
}

// ---------------- P1b: rms(k),rms(q), |k|^2, gates ----------------
__global__ void __launch_bounds__(256) p1b(const void* __restrict__ x,
                    const void* __restrict__ kn,
                    const void* __restrict__ qn,
                    const void* __restrict__ aw,
                    const void* __restrict__ tw,
                    const void* __restrict__ ew,
                    float* __restrict__ ws){
  int f = ((const int*)(ws+OFF_FLAG))[0];
  int tok = blockIdx.x; int tid = threadIdx.x;
  __shared__ float sm[8];
  float* krow = ws + OFF_K + (size_t)tok*512;
  float* qrow = ws + OFF_Q + (size_t)tok*512;
  float a = krow[tid], b = krow[tid+256];
  float ss = blockReduceSum(a*a+b*b, sm);
  float n = rsqrtf(ss*(1.f/512.f) + 1e-6f);
  float k1v = a*n*ldin(kn,tid,f);
  float k2v = b*n*ldin(kn,tid+256,f);
  krow[tid]=k1v; krow[tid+256]=k2v;
  float kn2 = blockReduceSum(k1v*k1v+k2v*k2v, sm);
  if(tid==0) ws[OFF_KN2+tok]=kn2;
  a = qrow[tid]; b = qrow[tid+256];
  ss = blockReduceSum(a*a+b*b, sm);
  n = rsqrtf(ss*(1.f/512.f)+1e-6f);
  qrow[tid]=a*n*ldin(qn,tid,f);
  qrow[tid+256]=b*n*ldin(qn,tid+256,f);
  float x1=ldin(x,(size_t)tok*512+tid,f), x2=ldin(x,(size_t)tok*512+tid+256,f);
  float td = blockReduceSum(x1*ldin(tw,tid,f) + x2*ldin(tw,tid+256,f), sm);
  float ad = blockReduceSum(x1*ldin(aw,tid,f) + x2*ldin(aw,tid+256,f), sm);
  float ed = blockReduceSum(x1*ldin(ew,tid,f) + x2*ldin(ew,tid+256,f), sm);
  if(tid==0){
    ws[OFF_TH+tok] = 0.01f/(1.f+expf(-td));
    ws[OFF_AL+tok] = 1.f/(1.f+expf(-ad));
    ws[OFF_ET+tok] = 1.f/(1.f+expf(-ed));
  }
}

// ---------------- K1: update W1(+ln) w/ chunk c-1 grads; z1,h for chunk c ----------------
__global__ void __launch_bounds__(256) k1_w1(float* __restrict__ ws, int c){
  unsigned short* bsw1 = (unsigned short*)(ws + OFF_BST);
  unsigned short* bmw1 = bsw1 + STSZ;
  int b = blockIdx.y, bx = blockIdx.x, tid = threadIdx.x;
  __shared__ float sE[32], sC[32], scal[3];
  if(c>0){
    const float* slab = ws + OFF_SLAB + ((long)(c-1)*B_ + b)*SLABSTR;
    if(tid<32){ sE[tid]=slab[128+tid]; sC[tid]=slab[160+tid]; }
    if(tid>=32 && tid<35) scal[tid-32]=slab[192+(tid-32)];
  }
  __syncthreads();
  float PE = c>0? scal[0]:1.f, PB = c>0? scal[1]:1.f, Q = c>0? scal[2]:0.f;
  if(bx==128){
    if(c>0){
      for(int d=tid; d<512; d+=256){
        float gE=0,gC=0;
        for(int u=0;u<32;u++){
          float dl = ws[OFF_DLN + ((size_t)(b*32+u))*512 + d];
          gE += sE[u]*dl; gC += sC[u]*dl;
        }
        size_t ix = OFF_SLN + (size_t)b*512 + d;
        float sv=ws[ix], mv=ws[ix + (OFF_MLN-OFF_SLN)];
        ws[ix] = PE*sv - gE;
        ws[ix + (OFF_MLN-OFF_SLN)] = PB*mv + Q*sv - gC;
      }
    }
    return;
  }
  __shared__ __align__(16) float kp[32][132], kc[32][132], mt[8][132];
  __shared__ float aE[8][32], aC[8][32], hred[32];
  int i0 = bx*8;
  int r = tid>>5, l = tid&31;
  if(c>0){
    float dv = ws[OFF_DHP + ((size_t)(b*I_ + i0 + r))*32 + l];
    aE[r][l] = sE[l]*dv; aC[r][l] = sC[l]*dv;
  }
  if(tid<32) hred[tid]=0.f;
  float z = 0.f;
  const float* Kbase = ws + OFF_K + (size_t)b*S_*D_;
  size_t srow = ((size_t)(b*I_ + i0 + r))*512;
  ushort4 sv4={0,0,0,0}, mv4, svn=sv4, mvn;
  if(c>0) sv4 = *(ushort4*)(bsw1 + srow + l*4);
  mv4 = *(ushort4*)(bmw1 + srow + l*4);
  for(int dt=0; dt<512; dt+=128){
    #pragma unroll
    for(int q=0;q<4;q++){
      int f4id = tid + 256*q;
      int u = f4id>>5, dq = f4id&31;
      if(c>0) *(float4*)&kp[u][dq*4] = *(const float4*)(Kbase + (size_t)((c-1)*32+u)*512 + dt + dq*4);
      if(c<16) *(float4*)&kc[u][dq*4] = *(const float4*)(Kbase + (size_t)(c*32+u)*512 + dt + dq*4);
    }
    if(dt<384){   // prefetch next tile's state
      if(c>0) svn = *(ushort4*)(bsw1 + srow + dt + 128 + l*4);
      mvn = *(ushort4*)(bmw1 + srow + dt + 128 + l*4);
    }
    __syncthreads();
    {
      float4 nm;
      if(c>0){
        float4 sv = u42f4(sv4), mv = u42f4(mv4);
        float4 gE={0,0,0,0}, gC={0,0,0,0};
        #pragma unroll
        for(int u=0;u<32;u++){
          float4 kv = *(float4*)&kp[u][l*4];
          float ae = aE[r][u], ac = aC[r][u];
          gE.x += ae*kv.x; gE.y += ae*kv.y; gE.z += ae*kv.z; gE.w += ae*kv.w;
          gC.x += ac*kv.x; gC.y += ac*kv.y; gC.z += ac*kv.z; gC.w += ac*kv.w;
        }
        float4 ns;
        ns.x = PE*sv.x - gE.x; ns.y = PE*sv.y - gE.y; ns.z = PE*sv.z - gE.z; ns.w = PE*sv.w - gE.w;
        nm.x = PB*mv.x + Q*sv.x - gC.x; nm.y = PB*mv.y + Q*sv.y - gC.y;
        nm.z = PB*mv.z + Q*sv.z - gC.z; nm.w = PB*mv.w + Q*sv.w - gC.w;
        *(ushort4*)(bsw1 + srow + dt + l*4) = f42u4(ns);
        *(ushort4*)(bmw1 + srow + dt + l*4) = f42u4(nm);
      } else {
        nm = u42f4(mv4);
      }
      *(float4*)&mt[r][l*4] = nm;
    }
    __syncthreads();
    if(c<16){
      #pragma unroll
      for(int d4=0; d4<32; d4++){
        float4 m4 = *(float4*)&mt[r][d4*4];
        float4 k4 = *(float4*)&kc[l][d4*4];     // l = token
        z += m4.x*k4.x + m4.y*k4.y + m4.z*k4.z + m4.w*k4.w;
      }
    }
    __syncthreads();
    sv4 = svn; mv4 = mvn;
  }
  if(c<16){
    size_t zb = (size_t)(b*I_ + i0 + r)*32 + l;
    ws[OFF_Z1 + zb] = z;
    float h = z/(1.f+expf(-z));
    (ws + OFF_H2 + (size_t)(c&1)*HSZ)[zb] = h;
    atomicAdd(&hred[l], h*h);
    __syncthreads();
    if(tid<32) atomicAdd(ws + OFF_SLAB + ((size_t)c*B_ + b)*SLABSTR + tid, hred[tid]);
  }
}

// ---------------- K2: update W2 w/ chunk c-1 grads; o = M2@h_c ----------------
__global__ void __launch_bounds__(256) k2_w2(float* __restrict__ ws, int c){
  unsigned short* bsw2 = (unsigned short*)(ws + OFF_BST) + (size_t)2*STSZ;
  unsigned short* bmw2 = bsw2 + STSZ;
  int b = blockIdx.y, bx = blockIdx.x, tid = threadIdx.x;
  int d0 = bx*8;
  __shared__ float sE[32], sC[32], scal[3];
  __shared__ __align__(16) float hp[32][132], hc[32][132], mt2[8][132];
  __shared__ float aE[8][32], aC[8][32];
  int r = tid>>5, l = tid&31;
  if(c>0){
    const float* slab = ws + OFF_SLAB + ((long)(c-1)*B_+b)*SLABSTR;
    if(tid<32){ sE[tid]=slab[128+tid]; sC[tid]=slab[160+tid]; }
    if(tid>=32&&tid<35) scal[tid-32]=slab[192+tid-32];
    __syncthreads();
    float dv = ws[OFF_DO + ((size_t)(b*32+l))*512 + d0 + r];
    aE[r][l] = sE[l]*dv; aC[r][l] = sC[l]*dv;
  }
  __syncthreads();
  float PE = c>0?scal[0]:1.f, PB=c>0?scal[1]:1.f, Q=c>0?scal[2]:0.f;
  float o = 0.f;
  const float* hprev = ws + OFF_H2 + (size_t)((c-1)&1)*HSZ;
  const float* hcur  = ws + OFF_H2 + (size_t)(c&1)*HSZ;
  size_t srow = ((size_t)(b*D_ + d0 + r))*1024;
  ushort4 sv4={0,0,0,0}, mv4, svn=sv4, mvn;
  if(c>0) sv4 = *(ushort4*)(bsw2 + srow + l*4);
  mv4 = *(ushort4*)(bmw2 + srow + l*4);
  for(int it=0; it<1024; it+=128){
    #pragma unroll
    for(int q=0;q<4;q++){
      int f4id = tid + 256*q;
      int ii = f4id>>3, tq = f4id&7;
      if(c>0){
        float4 v = *(const float4*)(hprev + (size_t)(b*I_+it+ii)*32 + tq*4);
        hp[tq*4+0][ii]=v.x; hp[tq*4+1][ii]=v.y; hp[tq*4+2][ii]=v.z; hp[tq*4+3][ii]=v.w;
      }
      if(c<16){
        float4 v = *(const float4*)(hcur + (size_t)(b*I_+it+ii)*32 + tq*4);
        hc[tq*4+0][ii]=v.x; hc[tq*4+1][ii]=v.y; hc[tq*4+2][ii]=v.z; hc[tq*4+3][ii]=v.w;
      }
    }
    if(it<896){
      if(c>0) svn = *(ushort4*)(bsw2 + srow + it + 128 + l*4);
      mvn = *(ushort4*)(bmw2 + srow + it + 128 + l*4);
    }
    __syncthreads();
    {
      float4 nm;
      if(c>0){
        float4 sv = u42f4(sv4), mv = u42f4(mv4);
        float4 gE={0,0,0,0}, gC={0,0,0,0};
        #pragma unroll
        for(int u=0;u<32;u++){
          float4 hv = *(float4*)&hp[u][l*4];
          float ae = aE[r][u], ac = aC[r][u];
          gE.x += ae*hv.x; gE.y += ae*hv.y; gE.z += ae*hv.z; gE.w += ae*hv.w;
          gC.x += ac*hv.x; gC.y += ac*hv.y; gC.z += ac*hv.z; gC.w += ac*hv.w;
        }
        float4 ns;
        ns.x = PE*sv.x - gE.x; ns.y = PE*sv.y - gE.y; ns.z = PE*sv.z - gE.z; ns.w = PE*sv.w - gE.w;
        nm.x = PB*mv.x + Q*sv.x - gC.x; nm.y = PB*mv.y + Q*sv.y - gC.y;
        nm.z = PB*mv.z + Q*sv.z - gC.z; nm.w = PB*mv.w + Q*sv.w - gC.w;
        *(ushort4*)(bsw2 + srow + it + l*4) = f42u4(ns);
        *(ushort4*)(bmw2 + srow + it + l*4) = f42u4(nm);
      } else {
        nm = u42f4(mv4);
      }
      *(float4*)&mt2[r][l*4] = nm;
    }
    __syncthreads();
    if(c<16){
      #pragma unroll
      for(int i4=0;i4<32;i4++){
        float4 m4 = *(float4*)&mt2[r][i4*4];
        float4 h4 = *(float4*)&hc[l][i4*4];   // l = token
        o += m4.x*h4.x + m4.y*h4.y + m4.z*h4.z + m4.w*h4.w;
      }
    }
    __syncthreads();
    sv4 = svn; mv4 = mvn;
  }
  if(c<16) ws[OFF_OB + ((size_t)(b*32+l))*512 + d0 + r] = o;
}

// ---------------- K3: per-token rms backward ----------------
__global__ void __launch_bounds__(256) k3_rms(float* __restrict__ ws, int c){
  int t = blockIdx.x, b = blockIdx.y, tid=threadIdx.x;
  __shared__ float sm[8];
  int tok = b*S_ + c*32 + t;
  const float* orow = ws + OFF_OB + ((size_t)(b*32+t))*512;
  const float* krow = ws + OFF_K + (size_t)tok*512;
  const float* vrow = ws + OFF_V + (size_t)tok*512;
  const float* lrow = ws + OFF_MLN + (size_t)b*512;
  float th = ws[OFF_TH + tok];
  float o1=orow[tid], o2=orow[tid+256];
  float mu = blockReduceSum(o1*o1+o2*o2, sm)*(1.f/512.f);
  float n = rsqrtf(mu + 1e-6f);
  float l1=lrow[tid], l2=lrow[tid+256];
  float k1=krow[tid], k2=krow[tid+256];
  float v1=vrow[tid], v2=vrow[tid+256];
  float c2 = 2.f*th*(1.f/512.f);
  float u1 = c2*(k1 + o1*n*l1 - v1);
  float u2 = c2*(k2 + o2*n*l2 - v2);
  float s1 = blockReduceSum(u1*l1*o1 + u2*l2*o2, sm);
  float dln1 = u1*o1*n, dln2v = u2*o2*n;
  float f = n*n*n*s1*(1.f/512.f);
  float do1 = n*l1*u1 - f*o1;
  float do2 = n*l2*u2 - f*o2;
  float don2 = blockReduceSum(do1*do1+do2*do2, sm);
  float dl2s = blockReduceSum(dln1*dln1+dln2v*dln2v, sm);
  float* dorow = ws + OFF_DO + ((size_t)(b*32+t))*512;
  float* dlrow = ws + OFF_DLN + ((size_t)(b*32+t))*512;
  dorow[tid]=do1; dorow[tid+256]=do2;
  dlrow[tid]=dln1; dlrow[tid+256]=dln2v;
  if(tid==0){
    float* slab = ws + OFF_SLAB + ((size_t)c*B_+b)*SLABSTR;
    slab[64+t]=don2; slab[96+t]=dl2s;
  }
}

// ---------------- K4: dh = M2^T do, dhp, grad-norm + scan scalars ----------------
__global__ void __launch_bounds__(256) k4_dh(float* __restrict__ ws, int c){
  unsigned short* bmw2 = (unsigned short*)(ws + OFF_BST) + (size_t)3*STSZ;
  int bx = blockIdx.x, b = blockIdx.y, tid = threadIdx.x;
  int i0 = bx*16;
  __shared__ __align__(16) float dol[32][132], m2[16][132];
  __shared__ float red[32], coefl[32], bsufl[32];
  __shared__ int lastf;
  int r = tid>>5, t = tid&31;
  float dh0=0, dh1=0;
  for(int dt=0; dt<512; dt+=128){
    #pragma unroll
    for(int q=0;q<4;q++){
      int f4id = tid + 256*q;
      int tt = f4id>>5, dq = f4id&31;
      *(float4*)&dol[tt][dq*4] = *(const float4*)(ws + OFF_DO + (size_t)(b*32+tt)*512 + dt + dq*4);
    }
    #pragma unroll
    for(int q=0;q<2;q++){
      int f4id = tid + 256*q;
      int dd = f4id>>2, iq = f4id&3;
      float4 v = u42f4(*(const ushort4*)(bmw2 + (size_t)(b*D_+dt+dd)*1024 + i0 + iq*4));
      m2[iq*4+0][dd]=v.x; m2[iq*4+1][dd]=v.y; m2[iq*4+2][dd]=v.z; m2[iq*4+3][dd]=v.w;
    }
    __syncthreads();
    #pragma unroll
    for(int d4=0; d4<32; d4++){
      float4 dv = *(float4*)&dol[t][d4*4];
      float4 ma = *(float4*)&m2[r][d4*4];
      float4 mb = *(float4*)&m2[r+8][d4*4];
      dh0 += ma.x*dv.x + ma.y*dv.y + ma.z*dv.z + ma.w*dv.w;
      dh1 += mb.x*dv.x + mb.y*dv.y + mb.z*dv.z + mb.w*dv.w;
    }
    __syncthreads();
  }
  size_t zb0 = (size_t)(b*I_ + i0 + r)*32 + t;
  size_t zb1 = (size_t)(b*I_ + i0 + r + 8)*32 + t;
  float z0 = ws[OFF_Z1+zb0], z1v = ws[OFF_Z1+zb1];
  float s0 = 1.f/(1.f+expf(-z0)), s1g = 1.f/(1.f+expf(-z1v));
  float dp0 = dh0 * s0*(1.f + z0*(1.f-s0));
  float dp1 = dh1 * s1g*(1.f + z1v*(1.f-s1g));
  ws[OFF_DHP+zb0]=dp0; ws[OFF_DHP+zb1]=dp1;
  if(tid<32) red[tid]=0.f;
  __syncthreads();
  atomicAdd(&red[t], dp0*dp0+dp1*dp1);
  __syncthreads();
  float* slab = ws + OFF_SLAB + ((size_t)c*B_+b)*SLABSTR;
  if(tid<32) atomicAdd(&slab[32+tid], red[tid]);
  __threadfence();
  __syncthreads();
  if(tid==0){
    int* tick = (int*)(ws+OFF_TICK);
    lastf = (atomicAdd(&tick[c*B_+b],1) == 63) ? 1 : 0;
  }
  __syncthreads();
  if(!lastf) return;
  if(tid<32){
    float sqd = atomicAdd(&slab[32+tid], 0.f);
    float hn  = atomicAdd(&slab[0+tid], 0.f);
    float don2 = slab[64+tid], dl2 = slab[96+tid];
    float kn2 = ws[OFF_KN2 + b*S_ + c*32 + tid];
    float sq = sqd*kn2 + don2*hn + dl2;
    coefl[tid] = fminf(1.f/(sqrtf(sq)+1e-6f), 1.f);
  }
  __syncthreads();
  if(tid==0){
    const float* eta = ws + OFF_ET + b*S_ + c*32;
    const float* alp = ws + OFF_AL + b*S_ + c*32;
    float Esuf=1.f, Bsuf=1.f, cu=1.f;
    for(int u=31;u>=0;u--){
      if(u<31){
        float e1 = eta[u+1], b1 = 1.f-alp[u+1];
        Esuf *= e1; Bsuf *= b1;
        cu = Bsuf + e1*cu;
      }
      bsufl[u]=Bsuf;
      slab[128+u] = Esuf*coefl[u];
      slab[160+u] = cu*coefl[u];
    }
    float PE = Esuf*eta[0];
    float PB = Bsuf*(1.f-alp[0]);
    float Q=0.f, Epre=1.f;
    for(int t2=0;t2<32;t2++){ Epre *= eta[t2]; Q += bsufl[t2]*Epre; }
    slab[192]=PE; slab[193]=PB; slab[194]=Q;
  }
}

// ---------------- R1: hq = silu(q @ M1^T) ----------------
__global__ void __launch_bounds__(256) r1_gemm(float* __restrict__ ws){
  unsigned short* bmw1 = (unsigned short*)(ws + OFF_BST) + STSZ;
  int b = blockIdx.z;
  int s0 = blockIdx.x*64, i0 = blockIdx.y*64;
  __shared__ __align__(16) float qa[32][68], wa[32][68];
  float acc[4][4]={};
  int tx = threadIdx.x&15, ty = threadIdx.x>>4;
  const float* qb = ws + OFF_Q + (size_t)b*S_*D_;
  const unsigned short* w1b = bmw1 + (size_t)b*I_*D_;
  for(int k0=0;k0<512;k0+=32){
    #pragma unroll
    for(int q=0;q<2;q++){
      int f4id = threadIdx.x + 256*q;
      int row = f4id>>3, kq = f4id&7;
      float4 v = *(const float4*)(qb + (size_t)(s0+row)*512 + k0 + kq*4);
      qa[kq*4+0][row]=v.x; qa[kq*4+1][row]=v.y; qa[kq*4+2][row]=v.z; qa[kq*4+3][row]=v.w;
      float4 w = u42f4(*(const ushort4*)(w1b + (size_t)(i0+row)*512 + k0 + kq*4));
      wa[kq*4+0][row]=w.x; wa[kq*4+1][row]=w.y; wa[kq*4+2][row]=w.z; wa[kq*4+3][row]=w.w;
    }
    __syncthreads();
    #pragma unroll
    for(int kk=0;kk<32;kk++){
      float4 a4 = *(float4*)&qa[kk][ty*4];
      float4 b4 = *(float4*)&wa[kk][tx*4];
      float a_[4]={a4.x,a4.y,a4.z,a4.w}, b_[4]={b4.x,b4.y,b4.z,b4.w};
      #pragma unroll
      for(int i=0;i<4;i++)
        #pragma unroll
        for(int j=0;j<4;j++) acc[i][j]+=a_[i]*b_[j];
    }
    __syncthreads();
  }
  float* hq = ws + OFF_HQ + (size_t)b*S_*I_;
  #pragma unroll
  for(int i=0;i<4;i++){
    float4 o4;
    o4.x = acc[i][0]/(1.f+expf(-acc[i][0])); o4.y = acc[i][1]/(1.f+expf(-acc[i][1]));
    o4.z = acc[i][2]/(1.f+expf(-acc[i][2])); o4.w = acc[i][3]/(1.f+expf(-acc[i][3]));
    *(float4*)(hq + (size_t)(s0+ty*4+i)*1024 + i0 + tx*4) = o4;
  }
}

// ---------------- R2: oret = hq @ M2^T ----------------
__global__ void __launch_bounds__(256) r2_gemm(float* __restrict__ ws){
  unsigned short* bmw2 = (unsigned short*)(ws + OFF_BST) + (size_t)3*STSZ;
  int b=blockIdx.z;
  int s0=blockIdx.x*64, d0=blockIdx.y*64;
  __shared__ __align__(16) float ha[32][68], wa[32][68];
  float acc[4][4]={};
  int tx=threadIdx.x&15, ty=threadIdx.x>>4;
  const float* hq = ws + OFF_HQ + (size_t)b*S_*I_;
  const unsigned short* w2b = bmw2 + (size_t)b*D_*I_;
  for(int k0=0;k0<1024;k0+=32){
    #pragma unroll
    for(int q=0;q<2;q++){
      int f4id = threadIdx.x + 256*q;
      int row = f4id>>3, kq = f4id&7;
      float4 v = *(const float4*)(hq + (size_t)(s0+row)*1024 + k0 + kq*4);
      ha[kq*4+0][row]=v.x; ha[kq*4+1][row]=v.y; ha[kq*4+2][row]=v.z; ha[kq*4+3][row]=v.w;
      float4 w = u42f4(*(const ushort4*)(w2b + (size_t)(d0+row)*1024 + k0 + kq*4));
      wa[kq*4+0][row]=w.x; wa[kq*4+1][row]=w.y; wa[kq*4+2][row]=w.z; wa[kq*4+3][row]=w.w;
    }
    __syncthreads();
    #pragma unroll
    for(int kk=0;kk<32;kk++){
      float4 a4 = *(float4*)&ha[kk][ty*4];
      float4 b4 = *(float4*)&wa[kk][tx*4];
      float a_[4]={a4.x,a4.y,a4.z,a4.w}, b_[4]={b4.x,b4.y,b4.z,b4.w};
      #pragma unroll
      for(int i=0;i<4;i++)
        #pragma unroll
        for(int j=0;j<4;j++) acc[i][j]+=a_[i]*b_[j];
    }
    __syncthreads();
  }
  float* od = ws + OFF_ORET + (size_t)b*S_*D_;
  #pragma unroll
  for(int i=0;i<4;i++){
    float4 o4 = {acc[i][0],acc[i][1],acc[i][2],acc[i][3]};
    *(float4*)(od + (size_t)(s0+ty*4+i)*512 + d0 + tx*4) = o4;
  }
}

// ---------------- R3: out = q + rms(oret, Mln) ----------------
__global__ void __launch_bounds__(256) r3_out(float* __restrict__ ws, void* __restrict__ out){
  int f = ((const int*)(ws+OFF_FLAG))[0];
  int tok=blockIdx.x, tid=threadIdx.x;
  int b = tok >> 9;
  __shared__ float sm[8];
  const float* orow = ws + OFF_ORET + (size_t)tok*512;
  const float* qrow = ws + OFF_Q + (size_t)tok*512;
  const float* lrow = ws + OFF_MLN + (size_t)b*512;
  float o1=orow[tid], o2=orow[tid+256];
  float mu = blockReduceSum(o1*o1+o2*o2, sm)*(1.f/512.f);
  float n = rsqrtf(mu+1e-6f);
  float r1v = qrow[tid]     + o1*n*lrow[tid];
  float r2v = qrow[tid+256] + o2*n*lrow[tid+256];
  if(f){
    ((float*)out)[(size_t)tok*512+tid]     = r1v;
    ((float*)out)[(size_t)tok*512+tid+256] = r2v;
  } else {
    ((__hip_bfloat16*)out)[(size_t)tok*512+tid]     = __float2bfloat16(r1v);
    ((__hip_bfloat16*)out)[(size_t)tok*512+tid+256] = __float2bfloat16(r2v);
  }
}

extern "C" void kernel_launch(void* const* d_in, const int* in_sizes, int n_in,
                              void* d_out, int out_size, void* d_ws, size_t ws_size,
                              hipStream_t stream) {
  const void* x  = d_in[0];
  const void* wq = d_in[1];
  const void* wk = d_in[2];
  const void* wv = d_in[3];
  const void* qn = d_in[4];
  const void* kn = d_in[5];
  const void* aw = d_in[6];
  const void* tw = d_in[7];
  const void* ew = d_in[8];
  const void* w1 = d_in[9];
  const void* w2 = d_in[10];
  const void* ln = d_in[11];
  float* ws = (float*)d_ws;

  d0_detect<<<1,64,0,stream>>>(x, ws);
  p0_init<<<2048,256,0,stream>>>(ws, w1, w2, ln);
  p1a<<<dim3(32,8,3),256,0,stream>>>(x, wk, wv, wq, ws);
  p1b<<<2048,256,0,stream>>>(x, kn, qn, aw, tw, ew, ws);
  for(int c=0;c<=16;c++){
    k1_w1<<<dim3(129,4),256,0,stream>>>(ws, c);
    k2_w2<<<dim3(64,4),256,0,stream>>>(ws, c);
    if(c<16){
      k3_rms<<<dim3(32,4),256,0,stream>>>(ws, c);
      k4_dh<<<dim3(64,4),256,0,stream>>>(ws, c);
    }
  }
  r1_gemm<<<dim3(8,16,4),256,0,stream>>>(ws);
  r2_gemm<<<dim3(8,8,4),256,0,stream>>>(ws);
  r3_out<<<2048,256,0,stream>>>(ws, d_out);
}